// Round 1
// 200.581 us; speedup vs baseline: 1.0027x; 1.0027x over previous
//
#include <hip/hip_runtime.h>
#include <type_traits>

#define S_LEN 2048
#define HID   768
#define NHEAD 12
#define HDIM  64
#define BATCH 4

typedef __attribute__((ext_vector_type(4))) float float4v;
typedef __attribute__((ext_vector_type(8))) short short8;
typedef __attribute__((ext_vector_type(4))) short short4v;
typedef __attribute__((ext_vector_type(2))) int int2v;

__device__ __forceinline__ short f2b(float f) {
  unsigned u = __float_as_uint(f);
  u += 0x7fff + ((u >> 16) & 1);   // RNE
  return (short)(u >> 16);
}

__device__ __forceinline__ unsigned pkbf(float a, float b) {
#if __has_builtin(__builtin_amdgcn_cvt_pk_bf16_f32)
  typedef __attribute__((ext_vector_type(2))) __bf16 bf2;
  bf2 r = __builtin_amdgcn_cvt_pk_bf16_f32(a, b);
  return *(unsigned*)&r;
#else
  return ((unsigned)(unsigned short)f2b(a)) |
         (((unsigned)(unsigned short)f2b(b)) << 16);
#endif
}

__device__ __forceinline__ float fexp2(float x) {
#if __has_builtin(__builtin_amdgcn_exp2f)
  return __builtin_amdgcn_exp2f(x);
#else
  return __expf(x * 0.69314718056f);
#endif
}

// async global->LDS, 16 B per lane; lds base must be wave-uniform
__device__ __forceinline__ void g2l16(const short* g, short* l) {
  __builtin_amdgcn_global_load_lds(
      (const __attribute__((address_space(1))) void*)g,
      (__attribute__((address_space(3))) void*)l, 16, 0, 0);
}

// ---------------- fused pre-pass: cvt x + transpose both weights ----------------
__global__ __launch_bounds__(256) void prepass(const float* __restrict__ x,
                                               const float* __restrict__ w_qkv,
                                               const float* __restrict__ w_out,
                                               short* __restrict__ xb,
                                               short* __restrict__ wqkvT,
                                               short* __restrict__ woutT) {
  __shared__ float tile[64][65];
  const int blk = blockIdx.x;
  if (blk < 3072) {  // cvt: 2048 elems per block
    int i = blk * 2048 + threadIdx.x * 8;
    float4v a = *(const float4v*)&x[i];
    float4v b = *(const float4v*)&x[i + 4];
    short8 o;
#pragma unroll
    for (int j = 0; j < 4; j++) { o[j] = f2b(a[j]); o[j + 4] = f2b(b[j]); }
    *(short8*)&xb[i] = o;
    return;
  }
  const float* W; short* WT; int N_, scaleN, idx;
  if (blk < 3504) { idx = blk - 3072; W = w_qkv; WT = wqkvT; N_ = 3 * HID; scaleN = HID; }
  else            { idx = blk - 3504; W = w_out; WT = woutT; N_ = HID;     scaleN = 0;  }
  const int nblk = N_ / 64;
  const int n0 = (idx % nblk) * 64, k0 = (idx / nblk) * 64;
  const int tx = threadIdx.x & 63, ty = threadIdx.x >> 6;
#pragma unroll
  for (int r = 0; r < 16; r++) {
    int row = r * 4 + ty;
    tile[row][tx] = W[(size_t)(k0 + row) * N_ + n0 + tx];
  }
  __syncthreads();
#pragma unroll
  for (int r = 0; r < 16; r++) {
    int row = r * 4 + ty;
    float sc = (n0 + row < scaleN) ? 0.18033688011f : 1.0f;  // 0.125*log2e
    WT[(size_t)(n0 + row) * HID + k0 + tx] = f2b(tile[tx][row] * sc);
  }
}

// ---------------- bf16 GEMM: C[MxN] = A[MxK] * Bt[NxK]^T ----------
// 128x128 tile, BK=64 as two BK=32 sub-buffers (keeps [row][32] g2l16 layout),
// halving barrier count vs m97-style BK=32.
template <int OUT>
__global__ __launch_bounds__(256) void gemm_bt(const short* __restrict__ A,
                                               const short* __restrict__ Bt,
                                               float* __restrict__ Cf,
                                               short* __restrict__ Cq,
                                               short* __restrict__ vT,
                                               int M, int N, int K) {
  __shared__ __align__(16) short As[2][128 * 32];
  __shared__ __align__(16) short Bs[2][128 * 32];
  const int tid = threadIdx.x;
  const int w = tid >> 6, lane = tid & 63;
  const int quad = lane >> 4, lm = lane & 15;
  const int m0 = blockIdx.y * 128, n0 = blockIdx.x * 128;
  const int mo = (w & 1) * 64, no = (w >> 1) * 64;

  float4v acc[4][4];
#pragma unroll
  for (int i = 0; i < 4; i++)
#pragma unroll
    for (int j = 0; j < 4; j++) acc[i][j] = (float4v)0.0f;

  const int srow = w * 32 + (lane >> 2);
  const int scol = (lane & 3) * 8;
  const short* Ag = A + (size_t)(m0 + srow) * K + scol;
  const short* Bg = Bt + (size_t)(n0 + srow) * K + scol;

  for (int kb = 0; kb < K; kb += 64) {
#pragma unroll
    for (int s = 0; s < 2; s++) {
      short* Al = &As[s][(w * 32) * 32];
      short* Bl = &Bs[s][(w * 32) * 32];
      g2l16(Ag + kb + s * 32, Al);
      g2l16(Ag + kb + s * 32 + (size_t)16 * K, Al + 16 * 32);
      g2l16(Bg + kb + s * 32, Bl);
      g2l16(Bg + kb + s * 32 + (size_t)16 * K, Bl + 16 * 32);
    }
    __syncthreads();

#pragma unroll
    for (int s = 0; s < 2; s++) {
      short8 af[4], bf[4];
#pragma unroll
      for (int i = 0; i < 4; i++)
        af[i] = *(const short8*)&As[s][(mo + i * 16 + lm) * 32 + quad * 8];
#pragma unroll
      for (int j = 0; j < 4; j++)
        bf[j] = *(const short8*)&Bs[s][(no + j * 16 + lm) * 32 + quad * 8];
#pragma unroll
      for (int i = 0; i < 4; i++)
#pragma unroll
        for (int j = 0; j < 4; j++)
          acc[i][j] = __builtin_amdgcn_mfma_f32_16x16x32_bf16(af[i], bf[j], acc[i][j], 0, 0, 0);
    }
    __syncthreads();
  }

  if constexpr (OUT == 0) {
#pragma unroll
    for (int i = 0; i < 4; i++)
#pragma unroll
      for (int j = 0; j < 4; j++)
#pragma unroll
        for (int r = 0; r < 4; r++)
          Cf[(size_t)(m0 + mo + i * 16 + quad * 4 + r) * N + n0 + no + j * 16 + lm] =
              acc[i][j][r];
  } else {
    if (n0 >= 2 * HID) {  // V tile -> vT[b][h][d][s]
      const int b = m0 >> 11;
      const int s0 = (m0 & 2047) + mo + quad * 4;
#pragma unroll
      for (int i = 0; i < 4; i++)
#pragma unroll
        for (int j = 0; j < 4; j++) {
          int col = n0 + no + j * 16 + lm - 2 * HID;
          int h = col >> 6, d = col & 63;
          short4v pv;
#pragma unroll
          for (int r = 0; r < 4; r++) pv[r] = f2b(acc[i][j][r]);
          *(short4v*)&vT[((size_t)(b * NHEAD + h) * HDIM + d) * S_LEN + s0 + i * 16] = pv;
        }
    } else {  // Q/K tile -> qk[m][1536]
#pragma unroll
      for (int i = 0; i < 4; i++)
#pragma unroll
        for (int j = 0; j < 4; j++)
#pragma unroll
          for (int r = 0; r < 4; r++)
            Cq[(size_t)(m0 + mo + i * 16 + quad * 4 + r) * (2 * HID) + n0 + no + j * 16 + lm] =
                f2b(acc[i][j][r]);
    }
  }
}

// ---------------- MFMA flash attention (round-9: swizzled LDS + DMA staging) ----
// Changes vs round-7:
//   * Q fragments hoisted to registers (replaces the 16 VGPRs freed by
//     deleting kreg/vreg) -> Qs LDS tile gone, 2 fewer b128 reads/tile.
//   * K/V staged via global_load_lds double-buffer; swizzle applied by
//     permuting the per-lane GLOBAL source address (linear LDS dest, rule 21).
//     Removes 4 ds_write_b128 + PREFETCH address VALU per kt; one barrier/iter.
//   * XOR-swizzle ((row&7)<<4 on byte offset) on Ks/Vt/Ps, no padding:
//     all b128 reads <=2-way; LDS 46080 -> 40960 B -> 4 blocks/CU capacity.
__global__ __launch_bounds__(256) void attn_mfma(const short* __restrict__ qk,
                                                 const short* __restrict__ vT,
                                                 short* __restrict__ attnout) {
  __shared__ __align__(16) short Ks[2][64 * 64];   // [p][d], p key-permuted, swizzled
  __shared__ __align__(16) short Vt[2][64 * 64];   // [d][key], swizzled
  __shared__ __align__(16) short Ps[4][16 * 64];   // per-wave [m][key], swizzled

  const int tid = threadIdx.x;
  const int w = tid >> 6, lane = tid & 63;
  const int quad = lane >> 4, lm = lane & 15;
  const int bh = blockIdx.x, a = blockIdx.y;
  const int b = bh / NHEAD, h = bh % NHEAD;
  const int qtile[2] = {a, 31 - a};

  // ---- Q fragments in registers (no LDS round-trip) ----
  short8 aq[2][2];
#pragma unroll
  for (int t = 0; t < 2; t++)
#pragma unroll
    for (int kb = 0; kb < 2; kb++)
      aq[t][kb] = *(const short8*)&qk[(size_t)(b * S_LEN + qtile[t] * 64 + w * 16 + lm) * (2 * HID) +
                                      h * HDIM + kb * 32 + quad * 8];

  // ---- per-lane DMA source pointers (inverse swizzle + key permutation
  //      pre-applied to the global source; LDS dest stays linear) ----
  const size_t kbase = (size_t)(b * S_LEN) * (2 * HID) + HID + h * HDIM;
  const size_t vbase = (size_t)(b * NHEAD + h) * HDIM * S_LEN;
  const short* ksrc[2];
  const short* vsrc[2];
#pragma unroll
  for (int i = 0; i < 2; i++) {
    int c = (w * 2 + i) * 64 + lane;       // LDS 16B-chunk index this lane writes
    int row = c >> 3, slot = c & 7;
    int q8 = slot ^ (row & 7);             // inverse-swizzled source chunk
    int key = 4 * (row & 15) + (row >> 4); // key permutation (B-frag order)
    ksrc[i] = qk + kbase + (size_t)key * (2 * HID) + q8 * 8;
    vsrc[i] = vT + vbase + (size_t)row * S_LEN + q8 * 8;
  }

#define ISSUE(KT, BUF)                                                              \
  {                                                                                 \
    _Pragma("unroll") for (int i = 0; i < 2; i++) {                                 \
      g2l16(ksrc[i] + (size_t)(KT) * 64 * (2 * HID), &Ks[BUF][(w * 2 + i) * 512]);  \
      g2l16(vsrc[i] + (KT) * 64, &Vt[BUF][(w * 2 + i) * 512]);                      \
    }                                                                               \
  }

  float4v o_acc[2][4];
#pragma unroll
  for (int t = 0; t < 2; t++)
#pragma unroll
    for (int nt = 0; nt < 4; nt++) o_acc[t][nt] = (float4v)0.0f;
  float lsum[2][4];
#pragma unroll
  for (int t = 0; t < 2; t++)
#pragma unroll
    for (int r = 0; r < 4; r++) lsum[t][r] = 0.0f;

  const int ktmax = 32 - a;
  const int swx = (lm & 7) << 4;           // lane-constant read swizzle term
  int cur = 0;

  ISSUE(0, 0);

  for (int kt = 0; kt < ktmax; kt++) {
    // drain our in-flight DMA for buf[cur], and fence buf[cur^1] readers
    asm volatile("s_waitcnt vmcnt(0)" ::: "memory");
    __syncthreads();
    if (kt + 1 < ktmax) ISSUE(kt + 1, cur ^ 1);

#pragma unroll
    for (int t = 0; t < 2; t++) {
      if (t == 0 && kt > a) continue;   // tile A done after its diagonal
      float4v s_acc[4];
#pragma unroll
      for (int i = 0; i < 4; i++) s_acc[i] = (float4v)0.0f;
#pragma unroll
      for (int kb = 0; kb < 2; kb++) {
#pragma unroll
        for (int nt = 0; nt < 4; nt++) {
          short8 bk = *(const short8*)((const char*)&Ks[cur][0] +
                        ((nt * 16 + lm) << 7) + (((kb * 64 + quad * 16)) ^ swx));
          s_acc[nt] = __builtin_amdgcn_mfma_f32_16x16x32_bf16(aq[t][kb], bk, s_acc[nt], 0, 0, 0);
        }
      }

      const bool diag = (kt == qtile[t]);
#pragma unroll
      for (int r = 0; r < 4; r++) {
        float e[4];
#pragma unroll
        for (int nt = 0; nt < 4; nt++) {
          float v = fexp2(s_acc[nt][r]);  // Q pre-scaled by 0.125*log2e
          if (diag && (4 * lm + nt > w * 16 + quad * 4 + r)) v = 0.0f;
          lsum[t][r] += v;
          e[nt] = v;
        }
        int2v p2 = {(int)pkbf(e[0], e[1]), (int)pkbf(e[2], e[3])};
        int rowp = quad * 4 + r;
        *(int2v*)((char*)&Ps[w][0] + (rowp << 7) + ((lm * 8) ^ ((rowp & 7) << 4))) = p2;
      }

#pragma unroll
      for (int kb = 0; kb < 2; kb++) {
        short8 ap = *(const short8*)((const char*)&Ps[w][0] +
                      (lm << 7) + ((kb * 64 + quad * 16) ^ swx));
#pragma unroll
        for (int nt = 0; nt < 4; nt++) {
          short8 bv = *(const short8*)((const char*)&Vt[cur][0] +
                        ((nt * 16 + lm) << 7) + ((kb * 64 + quad * 16) ^ swx));
          o_acc[t][nt] = __builtin_amdgcn_mfma_f32_16x16x32_bf16(ap, bv, o_acc[t][nt], 0, 0, 0);
        }
      }
    }
    cur ^= 1;
  }

#pragma unroll
  for (int t = 0; t < 2; t++)
#pragma unroll
    for (int r = 0; r < 4; r++) {
#pragma unroll
      for (int off = 1; off < 16; off <<= 1)
        lsum[t][r] += __shfl_xor(lsum[t][r], off, 16);
      float inv = 1.0f / lsum[t][r];
      int rowg = b * S_LEN + qtile[t] * 64 + w * 16 + quad * 4 + r;
#pragma unroll
      for (int nt = 0; nt < 4; nt++)
        attnout[(size_t)rowg * HID + h * HDIM + nt * 16 + lm] =
            f2b(o_acc[t][nt][r] * inv);
    }
#undef ISSUE
}

extern "C" void kernel_launch(void* const* d_in, const int* in_sizes, int n_in,
                              void* d_out, int out_size, void* d_ws, size_t ws_size,
                              hipStream_t stream) {
  const float* x     = (const float*)d_in[0];
  const float* w_qkv = (const float*)d_in[1];
  const float* w_out = (const float*)d_in[2];
  float* out = (float*)d_out;

  const int M = BATCH * S_LEN;  // 8192
  short* qk     = (short*)d_ws;                       // [8192][1536] bf16
  short* attn   = qk + (size_t)M * 2 * HID;           // [8192][768]  bf16
  short* vT     = attn + (size_t)M * HID;             // [B][NH][64][2048] bf16
  short* xb     = vT + (size_t)M * HID;               // [8192][768]  bf16
  short* wqkvT  = xb + (size_t)M * HID;               // [2304][768]  bf16 (Q rows pre-scaled)
  short* woutT  = wqkvT + (size_t)(3 * HID) * HID;    // [768][768]   bf16

  prepass<<<3648, 256, 0, stream>>>(x, w_qkv, w_out, xb, wqkvT, woutT);

  gemm_bt<1><<<dim3(3 * HID / 128, M / 128), 256, 0, stream>>>(
      xb, wqkvT, nullptr, qk, vT, M, 3 * HID, HID);
  attn_mfma<<<dim3(BATCH * NHEAD, S_LEN / 128), 256, 0, stream>>>(qk, vT, attn);
  gemm_bt<0><<<dim3(HID / 128, M / 128), 256, 0, stream>>>(
      attn, woutT, out, nullptr, nullptr, M, HID, HID);
}

// Round 3
// 193.645 us; speedup vs baseline: 1.0386x; 1.0358x over previous
//
#include <hip/hip_runtime.h>
#include <type_traits>

#define S_LEN 2048
#define HID   768
#define NHEAD 12
#define HDIM  64
#define BATCH 4

typedef __attribute__((ext_vector_type(4))) float float4v;
typedef __attribute__((ext_vector_type(8))) short short8;
typedef __attribute__((ext_vector_type(4))) short short4v;
typedef __attribute__((ext_vector_type(2))) int int2v;

__device__ __forceinline__ short f2b(float f) {
  unsigned u = __float_as_uint(f);
  u += 0x7fff + ((u >> 16) & 1);   // RNE
  return (short)(u >> 16);
}

__device__ __forceinline__ unsigned pkbf(float a, float b) {
#if __has_builtin(__builtin_amdgcn_cvt_pk_bf16_f32)
  typedef __attribute__((ext_vector_type(2))) __bf16 bf2;
  bf2 r = __builtin_amdgcn_cvt_pk_bf16_f32(a, b);
  return *(unsigned*)&r;
#else
  return ((unsigned)(unsigned short)f2b(a)) |
         (((unsigned)(unsigned short)f2b(b)) << 16);
#endif
}

__device__ __forceinline__ float fexp2(float x) {
#if __has_builtin(__builtin_amdgcn_exp2f)
  return __builtin_amdgcn_exp2f(x);
#else
  return __expf(x * 0.69314718056f);
#endif
}

// async global->LDS, 16 B per lane; lds base must be wave-uniform
__device__ __forceinline__ void g2l16(const short* g, short* l) {
  __builtin_amdgcn_global_load_lds(
      (const __attribute__((address_space(1))) void*)g,
      (__attribute__((address_space(3))) void*)l, 16, 0, 0);
}

// ---------------- fused pre-pass: cvt x + transpose both weights ----------------
__global__ __launch_bounds__(256) void prepass(const float* __restrict__ x,
                                               const float* __restrict__ w_qkv,
                                               const float* __restrict__ w_out,
                                               short* __restrict__ xb,
                                               short* __restrict__ wqkvT,
                                               short* __restrict__ woutT) {
  __shared__ float tile[64][65];
  const int blk = blockIdx.x;
  if (blk < 3072) {  // cvt: 2048 elems per block
    int i = blk * 2048 + threadIdx.x * 8;
    float4v a = *(const float4v*)&x[i];
    float4v b = *(const float4v*)&x[i + 4];
    short8 o;
#pragma unroll
    for (int j = 0; j < 4; j++) { o[j] = f2b(a[j]); o[j + 4] = f2b(b[j]); }
    *(short8*)&xb[i] = o;
    return;
  }
  const float* W; short* WT; int N_, scaleN, idx;
  if (blk < 3504) { idx = blk - 3072; W = w_qkv; WT = wqkvT; N_ = 3 * HID; scaleN = HID; }
  else            { idx = blk - 3504; W = w_out; WT = woutT; N_ = HID;     scaleN = 0;  }
  const int nblk = N_ / 64;
  const int n0 = (idx % nblk) * 64, k0 = (idx / nblk) * 64;
  const int tx = threadIdx.x & 63, ty = threadIdx.x >> 6;
#pragma unroll
  for (int r = 0; r < 16; r++) {
    int row = r * 4 + ty;
    tile[row][tx] = W[(size_t)(k0 + row) * N_ + n0 + tx];
  }
  __syncthreads();
#pragma unroll
  for (int r = 0; r < 16; r++) {
    int row = r * 4 + ty;
    float sc = (n0 + row < scaleN) ? 0.18033688011f : 1.0f;  // 0.125*log2e
    WT[(size_t)(n0 + row) * HID + k0 + tx] = f2b(tile[tx][row] * sc);
  }
}

// ---------------- bf16 GEMM: C[MxN] = A[MxK] * Bt[NxK]^T ----------
// 128x128 tile, BK=64 as two BK=32 sub-buffers.  XCD-chunked block swizzle
// (bijective: nwg%8==0 for both launches) localizes A-panels per XCD L2.
template <int OUT>
__global__ __launch_bounds__(256) void gemm_bt(const short* __restrict__ A,
                                               const short* __restrict__ Bt,
                                               float* __restrict__ Cf,
                                               short* __restrict__ Cq,
                                               short* __restrict__ vT,
                                               int M, int N, int K) {
  __shared__ __align__(16) short As[2][128 * 32];
  __shared__ __align__(16) short Bs[2][128 * 32];
  const int tid = threadIdx.x;
  const int w = tid >> 6, lane = tid & 63;
  const int quad = lane >> 4, lm = lane & 15;

  const int gx = gridDim.x;
  const int nwg = gx * gridDim.y;
  int flat = blockIdx.y * gx + blockIdx.x;
  if ((nwg & 7) == 0) flat = (flat & 7) * (nwg >> 3) + (flat >> 3);
  const int m0 = (flat / gx) * 128, n0 = (flat % gx) * 128;
  const int mo = (w & 1) * 64, no = (w >> 1) * 64;

  float4v acc[4][4];
#pragma unroll
  for (int i = 0; i < 4; i++)
#pragma unroll
    for (int j = 0; j < 4; j++) acc[i][j] = (float4v)0.0f;

  const int srow = w * 32 + (lane >> 2);
  const int scol = (lane & 3) * 8;
  const short* Ag = A + (size_t)(m0 + srow) * K + scol;
  const short* Bg = Bt + (size_t)(n0 + srow) * K + scol;

  for (int kb = 0; kb < K; kb += 64) {
#pragma unroll
    for (int s = 0; s < 2; s++) {
      short* Al = &As[s][(w * 32) * 32];
      short* Bl = &Bs[s][(w * 32) * 32];
      g2l16(Ag + kb + s * 32, Al);
      g2l16(Ag + kb + s * 32 + (size_t)16 * K, Al + 16 * 32);
      g2l16(Bg + kb + s * 32, Bl);
      g2l16(Bg + kb + s * 32 + (size_t)16 * K, Bl + 16 * 32);
    }
    __syncthreads();

#pragma unroll
    for (int s = 0; s < 2; s++) {
      short8 af[4], bf[4];
#pragma unroll
      for (int i = 0; i < 4; i++)
        af[i] = *(const short8*)&As[s][(mo + i * 16 + lm) * 32 + quad * 8];
#pragma unroll
      for (int j = 0; j < 4; j++)
        bf[j] = *(const short8*)&Bs[s][(no + j * 16 + lm) * 32 + quad * 8];
#pragma unroll
      for (int i = 0; i < 4; i++)
#pragma unroll
        for (int j = 0; j < 4; j++)
          acc[i][j] = __builtin_amdgcn_mfma_f32_16x16x32_bf16(af[i], bf[j], acc[i][j], 0, 0, 0);
    }
    __syncthreads();
  }

  if constexpr (OUT == 0) {
#pragma unroll
    for (int i = 0; i < 4; i++)
#pragma unroll
      for (int j = 0; j < 4; j++)
#pragma unroll
        for (int r = 0; r < 4; r++)
          Cf[(size_t)(m0 + mo + i * 16 + quad * 4 + r) * N + n0 + no + j * 16 + lm] =
              acc[i][j][r];
  } else {
    if (n0 >= 2 * HID) {  // V tile -> vT[b][h][d][s]
      const int b = m0 >> 11;
      const int s0 = (m0 & 2047) + mo + quad * 4;
#pragma unroll
      for (int i = 0; i < 4; i++)
#pragma unroll
        for (int j = 0; j < 4; j++) {
          int col = n0 + no + j * 16 + lm - 2 * HID;
          int h = col >> 6, d = col & 63;
          short4v pv;
#pragma unroll
          for (int r = 0; r < 4; r++) pv[r] = f2b(acc[i][j][r]);
          *(short4v*)&vT[((size_t)(b * NHEAD + h) * HDIM + d) * S_LEN + s0 + i * 16] = pv;
        }
    } else {  // Q/K tile -> qk[m][1536]
#pragma unroll
      for (int i = 0; i < 4; i++)
#pragma unroll
        for (int j = 0; j < 4; j++)
#pragma unroll
          for (int r = 0; r < 4; r++)
            Cq[(size_t)(m0 + mo + i * 16 + quad * 4 + r) * (2 * HID) + n0 + no + j * 16 + lm] =
                f2b(acc[i][j][r]);
    }
  }
}

// ---------------- MFMA flash attention (round-10: VALU diet) ----
// vs round-9 (conflicts already 0, VALU-issue-bound at 53%):
//   * s_acc zero-init removed: persistent z4 register is the C operand of the
//     first-kb MFMA (-16 v_mov/pair).
//   * lsum via MFMA: one extra mfma per kb with an all-ones bf16 B-fragment
//     (register constant) accumulates the P row-sum in the matrix pipe
//     (-16 v_add/pair, no final shuffle reduce; denominator now uses the
//     same rounded-bf16 P as the numerator).
//   * all ds_read/ds_write addresses hoisted to per-lane base registers +
//     immediate offsets (swizzle XOR terms are lane-constant).
//   * DMA pointers bump by constant instead of KT-multiply.
//   * s_setprio(1) around both MFMA clusters (T5, +4-7% measured on attn).
__global__ __launch_bounds__(256) void attn_mfma(const short* __restrict__ qk,
                                                 const short* __restrict__ vT,
                                                 short* __restrict__ attnout) {
  __shared__ __align__(16) short Ks[2][64 * 64];   // [p][d], p key-permuted, swizzled
  __shared__ __align__(16) short Vt[2][64 * 64];   // [d][key], swizzled
  __shared__ __align__(16) short Ps[4][16 * 64];   // per-wave [m][key], swizzled

  const int tid = threadIdx.x;
  const int w = tid >> 6, lane = tid & 63;
  const int quad = lane >> 4, lm = lane & 15;
  const int bh = blockIdx.x, a = blockIdx.y;
  const int b = bh / NHEAD, h = bh % NHEAD;
  const int qtile[2] = {a, 31 - a};

  // ---- Q fragments in registers ----
  short8 aq[2][2];
#pragma unroll
  for (int t = 0; t < 2; t++)
#pragma unroll
    for (int kb = 0; kb < 2; kb++)
      aq[t][kb] = *(const short8*)&qk[(size_t)(b * S_LEN + qtile[t] * 64 + w * 16 + lm) * (2 * HID) +
                                      h * HDIM + kb * 32 + quad * 8];

  // ---- register constants ----
  const float4v z4 = (float4v)0.0f;       // C operand for first-kb MFMA
  short8 one8;                            // bf16 1.0 broadcast (B-frag of ones)
#pragma unroll
  for (int j = 0; j < 8; j++) one8[j] = (short)0x3F80;

  // ---- per-lane DMA source pointers (inverse swizzle + key permutation
  //      pre-applied; LDS dest linear; bump-by-constant each issue) ----
  const size_t kbase = (size_t)(b * S_LEN) * (2 * HID) + HID + h * HDIM;
  const size_t vbase = (size_t)(b * NHEAD + h) * HDIM * S_LEN;
  const short* kptr[2];
  const short* vptr[2];
#pragma unroll
  for (int i = 0; i < 2; i++) {
    int c = (w * 2 + i) * 64 + lane;       // LDS 16B-chunk index this lane writes
    int row = c >> 3, slot = c & 7;
    int q8 = slot ^ (row & 7);             // inverse-swizzled source chunk
    int key = 4 * (row & 15) + (row >> 4); // key permutation (B-frag order)
    kptr[i] = qk + kbase + (size_t)key * (2 * HID) + q8 * 8;
    vptr[i] = vT + vbase + (size_t)row * S_LEN + q8 * 8;
  }

#define ISSUE(BUF)                                                    \
  {                                                                   \
    _Pragma("unroll") for (int i = 0; i < 2; i++) {                   \
      g2l16(kptr[i], &Ks[BUF][(w * 2 + i) * 512]);                    \
      g2l16(vptr[i], &Vt[BUF][(w * 2 + i) * 512]);                    \
      kptr[i] += 64 * 2 * HID;                                        \
      vptr[i] += 64;                                                  \
    }                                                                 \
  }

  // ---- hoisted LDS read/write addressing (all kernel-invariant but cur) ----
  const int swx = (lm & 7) << 4;
  const int loff0 = (quad * 16) ^ swx;          // kb=0 lane part
  const int loff1 = (64 + quad * 16) ^ swx;     // kb=1 lane part
  const int rowK = lm << 7;
  const char* KsB = (const char*)&Ks[0][0];
  const char* VtB = (const char*)&Vt[0][0];
  const char* PsW = (const char*)&Ps[w][0];
  const char* pread0 = PsW + rowK + loff0;      // Ps A-frag reads
  const char* pread1 = PsW + rowK + loff1;
  char* pswa[4];                                // Ps writes (static-indexed)
#pragma unroll
  for (int r = 0; r < 4; r++) {
    int rowp = quad * 4 + r;
    pswa[r] = (char*)PsW + (rowp << 7) + ((lm * 8) ^ ((rowp & 7) << 4));
  }

  float4v o_acc[2][4];
#pragma unroll
  for (int t = 0; t < 2; t++)
#pragma unroll
    for (int nt = 0; nt < 4; nt++) o_acc[t][nt] = (float4v)0.0f;
  float4v o1[2];                                // P row-sum accumulators
  o1[0] = (float4v)0.0f;
  o1[1] = (float4v)0.0f;

  const int ktmax = 32 - a;
  int cur = 0;

  ISSUE(0);

  for (int kt = 0; kt < ktmax; kt++) {
    // drain our in-flight DMA for buf[cur], and fence buf[cur^1] readers
    asm volatile("s_waitcnt vmcnt(0)" ::: "memory");
    __syncthreads();
    if (kt + 1 < ktmax) ISSUE(cur ^ 1);

    const int coff = cur << 13;
    const char* kB0 = KsB + coff + rowK + loff0;
    const char* kB1 = KsB + coff + rowK + loff1;
    const char* vB0 = VtB + coff + rowK + loff0;
    const char* vB1 = VtB + coff + rowK + loff1;

#pragma unroll
    for (int t = 0; t < 2; t++) {
      if (t == 0 && kt > a) continue;   // tile A done after its diagonal
      float4v s_acc[4];
      __builtin_amdgcn_s_setprio(1);
#pragma unroll
      for (int nt = 0; nt < 4; nt++) {
        short8 bk = *(const short8*)(kB0 + nt * 2048);
        s_acc[nt] = __builtin_amdgcn_mfma_f32_16x16x32_bf16(aq[t][0], bk, z4, 0, 0, 0);
      }
#pragma unroll
      for (int nt = 0; nt < 4; nt++) {
        short8 bk = *(const short8*)(kB1 + nt * 2048);
        s_acc[nt] = __builtin_amdgcn_mfma_f32_16x16x32_bf16(aq[t][1], bk, s_acc[nt], 0, 0, 0);
      }
      __builtin_amdgcn_s_setprio(0);

      const bool diag = (kt == qtile[t]);
#pragma unroll
      for (int r = 0; r < 4; r++) {
        float e[4];
#pragma unroll
        for (int nt = 0; nt < 4; nt++) {
          float v = fexp2(s_acc[nt][r]);  // Q pre-scaled by 0.125*log2e
          if (diag && (4 * lm + nt > w * 16 + quad * 4 + r)) v = 0.0f;
          e[nt] = v;
        }
        int2v p2 = {(int)pkbf(e[0], e[1]), (int)pkbf(e[2], e[3])};
        *(int2v*)pswa[r] = p2;  // key = 4*lm+nt
      }

      __builtin_amdgcn_s_setprio(1);
#pragma unroll
      for (int kb = 0; kb < 2; kb++) {
        short8 ap = *(const short8*)(kb ? pread1 : pread0);
        const char* vB = kb ? vB1 : vB0;
        o1[t] = __builtin_amdgcn_mfma_f32_16x16x32_bf16(ap, one8, o1[t], 0, 0, 0);
#pragma unroll
        for (int nt = 0; nt < 4; nt++) {
          short8 bv = *(const short8*)(vB + nt * 2048);
          o_acc[t][nt] = __builtin_amdgcn_mfma_f32_16x16x32_bf16(ap, bv, o_acc[t][nt], 0, 0, 0);
        }
      }
      __builtin_amdgcn_s_setprio(0);
    }
    cur ^= 1;
  }

#pragma unroll
  for (int t = 0; t < 2; t++)
#pragma unroll
    for (int r = 0; r < 4; r++) {
      float inv = 1.0f / o1[t][r];        // row-sum from ones-MFMA (col-uniform)
      int rowg = b * S_LEN + qtile[t] * 64 + w * 16 + quad * 4 + r;
#pragma unroll
      for (int nt = 0; nt < 4; nt++)
        attnout[(size_t)rowg * HID + h * HDIM + nt * 16 + lm] =
            f2b(o_acc[t][nt][r] * inv);
    }
#undef ISSUE
}

extern "C" void kernel_launch(void* const* d_in, const int* in_sizes, int n_in,
                              void* d_out, int out_size, void* d_ws, size_t ws_size,
                              hipStream_t stream) {
  const float* x     = (const float*)d_in[0];
  const float* w_qkv = (const float*)d_in[1];
  const float* w_out = (const float*)d_in[2];
  float* out = (float*)d_out;

  const int M = BATCH * S_LEN;  // 8192
  short* qk     = (short*)d_ws;                       // [8192][1536] bf16
  short* attn   = qk + (size_t)M * 2 * HID;           // [8192][768]  bf16
  short* vT     = attn + (size_t)M * HID;             // [B][NH][64][2048] bf16
  short* xb     = vT + (size_t)M * HID;               // [8192][768]  bf16
  short* wqkvT  = xb + (size_t)M * HID;               // [2304][768]  bf16 (Q rows pre-scaled)
  short* woutT  = wqkvT + (size_t)(3 * HID) * HID;    // [768][768]   bf16

  prepass<<<3648, 256, 0, stream>>>(x, w_qkv, w_out, xb, wqkvT, woutT);

  gemm_bt<1><<<dim3(3 * HID / 128, M / 128), 256, 0, stream>>>(
      xb, wqkvT, nullptr, qk, vT, M, 3 * HID, HID);
  attn_mfma<<<dim3(BATCH * NHEAD, S_LEN / 128), 256, 0, stream>>>(qk, vT, attn);
  gemm_bt<0><<<dim3(HID / 128, M / 128), 256, 0, stream>>>(
      attn, woutT, out, nullptr, nullptr, M, HID, HID);
}